// Round 2
// baseline (1370.660 us; speedup 1.0000x reference)
//
#include <hip/hip_runtime.h>
#include <hip/hip_bf16.h>
#include <cmath>

#define HWPX (1024*1024)
#define NOBJ 256
#define DDIM 512
#define PXT 2   // pixels per thread in apply

// ---------------------------------------------------------------------------
// Detect mask storage layout: bool (1 byte/elem) vs int32 (4 bytes/elem).
// int32 {0,1} -> every 32-bit word <= 1. Packed bool bytes -> some of the
// first 256 words exceed 1 with probability 1 - 8^-256.
// flag = 1 -> bool/byte layout, flag = 0 -> int32 layout.
// ---------------------------------------------------------------------------
__global__ __launch_bounds__(256) void detect_kernel(const unsigned int* __restrict__ m,
                                                     int* __restrict__ flag) {
    __shared__ int s;
    if (threadIdx.x == 0) s = 0;
    __syncthreads();
    if (m[threadIdx.x] > 1u) atomicOr(&s, 1);
    __syncthreads();
    if (threadIdx.x == 0) *flag = s;
}

// ---------------------------------------------------------------------------
// Stage 1: per object n (one 64-lane wave per object):
//   k = argmax(attr[n]@selector_w + selector_b + gumbel[n])   (TEMP = 1)
//   p = attr[n] @ param_w[:, 4k:4k+4] + param_b[4k:4k+4]
// Collapse affine ops to (A,B); tanh_mod keeps raw params (kind 6).
// ---------------------------------------------------------------------------
__global__ __launch_bounds__(64) void prep_kernel(
    const float* __restrict__ attr,    // (256,512)
    const float* __restrict__ selw,    // (512,8)
    const float* __restrict__ selb,    // (8)
    const float* __restrict__ gumbel,  // (256,8)
    const float* __restrict__ pw,      // (512,32)
    const float* __restrict__ pb,      // (32)
    float4* __restrict__ coef,
    int* __restrict__ kindArr)
{
    const int n = blockIdx.x;
    const int l = threadIdx.x;  // 0..63

    float a[8];
#pragma unroll
    for (int j = 0; j < 8; ++j) a[j] = attr[n * DDIM + l + 64 * j];

    float best = -1e30f;
    int bestk = 0;
#pragma unroll
    for (int k = 0; k < 8; ++k) {
        float s = 0.f;
#pragma unroll
        for (int j = 0; j < 8; ++j) s += a[j] * selw[(l + 64 * j) * 8 + k];
#pragma unroll
        for (int off = 32; off; off >>= 1) s += __shfl_xor(s, off);
        float v = s + selb[k] + gumbel[n * 8 + k];
        if (v > best) { best = v; bestk = k; }
    }
    bestk = __shfl(bestk, 0);  // lanes agree modulo last-ulp; take lane 0's pick

    float p[4];
#pragma unroll
    for (int qi = 0; qi < 4; ++qi) {
        float s = 0.f;
#pragma unroll
        for (int j = 0; j < 8; ++j) s += a[j] * pw[(l + 64 * j) * 32 + bestk * 4 + qi];
#pragma unroll
        for (int off = 32; off; off >>= 1) s += __shfl_xor(s, off);
        p[qi] = s + pb[bestk * 4 + qi];
    }

    if (l == 0) {
        float A = 1.f, B = 0.f;
        switch (bestk) {
            case 0: A = 0.f;  B = p[0]; break;                       // recolor
            case 1: A = 1.f;  B = p[0]; break;                       // add
            case 2: A = p[1]; B = 0.f;  break;                       // scale
            case 3: A = p[0]; B = p[1]; break;                       // affine
            case 4: { float aa = 1.f / (1.f + expf(-p[2]));          // blend
                      A = 1.f - aa; B = aa * p[0]; } break;
            case 5: A = -1.f; B = p[0]; break;                       // invert
            case 6: break;                                           // tanh_mod
            default: A = 1.f; B = p[0] * p[1]; break;                // offset
        }
        if (bestk == 6) {
            coef[n] = make_float4(p[0], p[1], p[2], p[3]);
            kindArr[n] = 6;
        } else {
            coef[n] = make_float4(A, B, 0.f, 0.f);
            kindArr[n] = 0;
        }
    }
}

// ---------------------------------------------------------------------------
// Stage 2 (fused gather + scan). Each thread owns PXT=2 pixels.
// Phase 1: pack this thread's 256 mask bits/pixel into 8 u32 registers.
//   Inner 32-iter loops are fully unrolled -> 32 independent loads in
//   flight per burst (deep MLP), compile-time bit shifts, no scratch.
// Phase 2: sequential 256-op scan from registers; per-object coeffs from
//   LDS (wave-uniform broadcast reads, conflict-free).
// ---------------------------------------------------------------------------
__global__ __launch_bounds__(256) void apply_kernel(
    const float* __restrict__ canvas,
    const unsigned char* __restrict__ masksB,
    const float4* __restrict__ coef,
    const int* __restrict__ kindArr,
    const int* __restrict__ flagP,
    float* __restrict__ out)
{
    __shared__ float4 sCoef[NOBJ];
    __shared__ int    sKind[NOBJ];
    const int t = threadIdx.x;
    sCoef[t] = coef[t];
    sKind[t] = kindArr[t];
    __syncthreads();

    const size_t base = ((size_t)blockIdx.x * 256 + t) * PXT;

    float2 cv = *(const float2*)(canvas + base);
    float c0 = cv.x, c1 = cv.y;

    unsigned bits0[8], bits1[8];

    const int isBool = __builtin_amdgcn_readfirstlane(*flagP);

    if (isBool) {
        const unsigned char* mp = masksB + base;
#pragma unroll
        for (int w = 0; w < 8; ++w) {
            unsigned a0 = 0, a1 = 0;
#pragma unroll
            for (int j = 0; j < 32; ++j) {
                const int i = w * 32 + j;
                unsigned short m = *(const unsigned short*)(mp + (size_t)i * HWPX);
                a0 |= (unsigned)((m & 0x00FFu) ? 1u : 0u) << j;
                a1 |= (unsigned)((m & 0xFF00u) ? 1u : 0u) << j;
            }
            bits0[w] = a0; bits1[w] = a1;
        }
    } else {
        const int* mi = (const int*)masksB;
#pragma unroll
        for (int w = 0; w < 8; ++w) {
            unsigned a0 = 0, a1 = 0;
#pragma unroll
            for (int j = 0; j < 32; ++j) {
                const int i = w * 32 + j;
                int2 m = *(const int2*)(mi + (size_t)i * HWPX + base);
                a0 |= (m.x ? 1u : 0u) << j;
                a1 |= (m.y ? 1u : 0u) << j;
            }
            bits0[w] = a0; bits1[w] = a1;
        }
    }

    // Sequential masked-op scan; op type/coeffs are grid-uniform per object.
#pragma unroll
    for (int w = 0; w < 8; ++w) {
        const unsigned b0 = bits0[w], b1 = bits1[w];
        for (int j = 0; j < 32; ++j) {
            const int i = w * 32 + j;
            float4 q = sCoef[i];
            float v0, v1;
            if (sKind[i] == 6) {
                float e0 = __expf(2.0f * fmaf(c0, q.x, q.y));
                float e1 = __expf(2.0f * fmaf(c1, q.x, q.y));
                float t0 = 1.0f - 2.0f / (e0 + 1.0f);   // tanh
                float t1 = 1.0f - 2.0f / (e1 + 1.0f);
                v0 = fmaf(t0, q.z, q.w);
                v1 = fmaf(t1, q.z, q.w);
            } else {
                v0 = fmaf(c0, q.x, q.y);
                v1 = fmaf(c1, q.x, q.y);
            }
            c0 = ((b0 >> j) & 1u) ? v0 : c0;
            c1 = ((b1 >> j) & 1u) ? v1 : c1;
        }
    }

    *(float2*)(out + base) = make_float2(c0, c1);
}

extern "C" void kernel_launch(void* const* d_in, const int* in_sizes, int n_in,
                              void* d_out, int out_size, void* d_ws, size_t ws_size,
                              hipStream_t stream) {
    const float* canvas        = (const float*)d_in[0];
    const float* attr          = (const float*)d_in[1];
    const unsigned char* masks = (const unsigned char*)d_in[2];
    const float* gumbel        = (const float*)d_in[3];
    const float* selw          = (const float*)d_in[4];
    const float* selb          = (const float*)d_in[5];
    const float* pw            = (const float*)d_in[6];
    const float* pb            = (const float*)d_in[7];
    float* out = (float*)d_out;

    float4* coef = (float4*)d_ws;
    int* kindArr = (int*)((char*)d_ws + NOBJ * sizeof(float4));
    int* flag = kindArr + NOBJ;

    detect_kernel<<<1, 256, 0, stream>>>((const unsigned int*)masks, flag);
    prep_kernel<<<NOBJ, 64, 0, stream>>>(attr, selw, selb, gumbel, pw, pb, coef, kindArr);
    apply_kernel<<<HWPX / (256 * PXT), 256, 0, stream>>>(canvas, masks, coef, kindArr, flag, out);
}